// Round 9
// baseline (845.998 us; speedup 1.0000x reference)
//
#include <hip/hip_runtime.h>
#include <hip/hip_bf16.h>

typedef __hip_bfloat16 bf16;
typedef unsigned short ushort;
typedef __attribute__((ext_vector_type(8))) short short8v;   // 8 bf16 = 4 VGPR
typedef __attribute__((ext_vector_type(4))) float float4v;

__device__ __forceinline__ float b2f(bf16 v){ return __bfloat162float(v); }
__device__ __forceinline__ float sigm(float x){ return 1.0f/(1.0f+__expf(-x)); }
__device__ __forceinline__ float tanhc(float x){
  x = fminf(15.0f, fmaxf(-15.0f, x));
  float e = __expf(2.0f*x);
  return (e-1.0f)/(e+1.0f);
}
__device__ __forceinline__ ushort f2bu(float f){
  bf16 h = __float2bfloat16(f); return *reinterpret_cast<ushort*>(&h);
}
__device__ __forceinline__ float bu2f(ushort u){
  return __uint_as_float(((unsigned)u)<<16);
}
__device__ __forceinline__ short8v ldfrag(const ushort* p){
  return *reinterpret_cast<const short8v*>(p);
}

// ---------------------------------------------------------------------------
// ws layout (float offsets)
// ---------------------------------------------------------------------------
#define WS_SMALL   0          // 262144 f32 small weights
#define WS_FLAG    262144
#define WS_H       262208     // h,c,m f32 states (h slot legacy-zeroed)
#define WS_C       524352
#define WS_M       786496
#define WS_HNEW    1048640    // 262144 f32 cell output h_new
#define WS_QB16    1310784    // 65536 f = [b][n][32] bf16 zero-padded
#define WS_KHB16   1376320    // 65536
#define WS_KMB16   1441856    // 65536
#define WS_VTH16   1507392    // 131072 f = [b][c][1024] bf16
#define WS_VTM16   1638464    // 131072
#define WS_ZCAT    1769536    // 524288
#define WS_ZWT     2293824    // 16384
#define WS_MW4     2310208    // 36864
#define WS_WAHI    2347072    // 147456 f (294912 bf16)
#define WS_WALO    2494528    // 147456
#define WS_XTHI    2641984    // 1048576
#define WS_XTLO    3690560    // 1048576
#define WS_HTHI    4739136    // 131072
#define WS_HTLO    4870208    // 131072 -> total 5001280 f = 20 MB
// small-weight offsets inside WS_SMALL
#define O_CB    0
#define O_WCI   256
#define O_WCF   65792
#define O_WCO   131328
#define O_QW    196864
#define O_QB    197888
#define O_KW    197904
#define O_KB    198928
#define O_K2W   198944
#define O_K2B   199968
#define O_VW    199984
#define O_VB    204080
#define O_V2W   204144
#define O_V2B   208240
#define O_ZW    208304
#define O_ZB    224688
#define O_MW    224816
#define O_MB    261680

// ---------------------------------------------------------------------------
// dtype probe (f32 vs bf16 input data)
// ---------------------------------------------------------------------------
__global__ void k_probe(const unsigned int* __restrict__ Xu, int* __restrict__ flag){
  __shared__ int cnt;
  if (threadIdx.x == 0) cnt = 0;
  __syncthreads();
  unsigned int u = Xu[threadIdx.x];
  float f = __uint_as_float((u & 0xffffu) << 16);
  int bad = (fabsf(f) <= 1e4f) ? 0 : 1;
  atomicAdd(&cnt, bad);
  __syncthreads();
  if (threadIdx.x == 0) *flag = (cnt > 16) ? 1 : 0;
}

// ---------------------------------------------------------------------------
// convert the 18 small inputs into f32 copies in ws
// ---------------------------------------------------------------------------
struct P18 { const void* p[18]; };

__global__ __launch_bounds__(256) void k_wconv(P18 pk, const int* __restrict__ flagp,
                                               float* __restrict__ dst){
  const int ns[18]   = {256,65536,65536,65536,1024,16,1024,16,1024,16,
                        4096,64,4096,64,16384,128,36864,192};
  const int offs[18] = {O_CB,O_WCI,O_WCF,O_WCO,O_QW,O_QB,O_KW,O_KB,O_K2W,O_K2B,
                        O_VW,O_VB,O_V2W,O_V2B,O_ZW,O_ZB,O_MW,O_MB};
  int y = blockIdx.y;
  int n = ns[y];
  int flag = *flagp;
  const void* src = pk.p[y];
  for (int i = blockIdx.x*256 + threadIdx.x; i < n; i += gridDim.x*256){
    float v = flag ? ((const float*)src)[i] : b2f(((const bf16*)src)[i]);
    dst[offs[y] + i] = v;
  }
}

// transpose z_w into [k][r]; pack m_w into mw4[(k4*192 + r)*4 + q]
__global__ __launch_bounds__(256) void k_wtrans(float* __restrict__ ws){
  int i = blockIdx.x*256 + threadIdx.x;
  if (i < 16384){
    int k = i >> 7, r = i & 127;
    ws[WS_ZWT + k*128 + r] = ws[O_ZW + r*128 + k];
  }
  if (i < 36864){
    int q = i & 3; int rest = i >> 2; int r = rest % 192; int k4 = rest / 192;
    ws[WS_MW4 + i] = ws[O_MW + r*192 + k4*4 + q];
  }
}

// ---------------------------------------------------------------------------
// init: zero h,c,m + hT; build MFMA weight layout wA (hi/lo)
// ---------------------------------------------------------------------------
__global__ __launch_bounds__(256) void k_init(const void* __restrict__ conv_w,
                                              const int* __restrict__ flagp,
                                              float* __restrict__ ws){
  int i = blockIdx.x*256 + threadIdx.x;
  int flag = *flagp;
  if (i < 786432) ws[WS_H + i] = 0.0f;
  if (i < 294912){
    int ci = i & 127;
    int j = i >> 7;
    int mm = j & 255, p = j >> 8;
    int cc = mm >> 2, g = mm & 3;
    int si = ((g*64 + cc)*128 + ci)*9 + p;
    ushort* wah = (ushort*)(ws + WS_WAHI);
    ushort* wal = (ushort*)(ws + WS_WALO);
    if (flag){
      float f = ((const float*)conv_w)[si];
      ushort hi = f2bu(f);
      wah[i] = hi;
      wal[i] = f2bu(f - bu2f(hi));
    } else {
      wah[i] = ((const ushort*)conv_w)[si];
    }
  }
  if (i < 131072){
    ((unsigned*)(ws + WS_HTHI))[i] = 0u;
    ((unsigned*)(ws + WS_HTLO))[i] = 0u;
  }
}

// ---------------------------------------------------------------------------
// X transpose: XT[b][t][px][ci]
// ---------------------------------------------------------------------------
__global__ __launch_bounds__(256) void k_xt(const void* __restrict__ Xraw,
                                            const int* __restrict__ flagp,
                                            float* __restrict__ ws){
  __shared__ ushort hi_s[64][66];
  __shared__ ushort lo_s[64][66];
  int pt = blockIdx.x, s = blockIdx.y;
  int b = s >> 3, t = s & 7;
  int flag = *flagp;
  int tid = threadIdx.x;
  for (int k = 0; k < 16; ++k){
    int idx = tid + k*256;
    int ci = idx >> 6, pxl = idx & 63;
    size_t si = ((size_t)(b*64 + ci)*8 + t)*1024 + pt*64 + pxl;
    if (flag){
      float f = ((const float*)Xraw)[si];
      ushort h = f2bu(f);
      hi_s[pxl][ci] = h;
      lo_s[pxl][ci] = f2bu(f - bu2f(h));
    } else {
      hi_s[pxl][ci] = ((const ushort*)Xraw)[si];
    }
  }
  __syncthreads();
  ushort* xh = (ushort*)(ws + WS_XTHI) + ((size_t)s*1024 + pt*64)*64;
  ushort* xl = (ushort*)(ws + WS_XTLO) + ((size_t)s*1024 + pt*64)*64;
  for (int k = 0; k < 16; ++k){
    int idx = tid + k*256;
    int pxl = idx >> 6, ci = idx & 63;
    xh[pxl*64 + ci] = hi_s[pxl][ci];
    if (flag) xl[pxl*64 + ci] = lo_s[pxl][ci];
  }
}

// ---------------------------------------------------------------------------
// conv 3x3 + peephole LSTM via MFMA implicit GEMM.
// grid (64 ntiles of 16px, 4 b) = 256 blocks, block 512 = 8 waves.
// Wave w owns m rows [w*32, w*32+32); B halo staged in LDS.
// bf16 path is BRANCH-FREE with explicit double-buffered A prefetch
// (the R8 41us stall was the in-loop flag branch blocking load hoisting).
// ---------------------------------------------------------------------------
__global__ __launch_bounds__(512, 4) void k_conv_mfma(
  const int* __restrict__ flagp,
  const ushort* __restrict__ wa_hi, const ushort* __restrict__ wa_lo,
  const ushort* __restrict__ xt_hi, const ushort* __restrict__ xt_lo,
  const ushort* __restrict__ ht_hi, const ushort* __restrict__ ht_lo,
  const float* __restrict__ smalls, float* __restrict__ cst,
  float* __restrict__ hnew, int t)
{
  __shared__ ushort bsm[54*264];
  int nt = blockIdx.x, b = blockIdx.y;
  int tid = threadIdx.x;
  int flag = *flagp;
  int ytile = nt >> 1, x0 = (nt & 1) * 16;

  const ushort* xb  = xt_hi + ((size_t)(b*8 + t))*65536;
  const ushort* xlb = xt_lo + ((size_t)(b*8 + t))*65536;
  const ushort* hb  = ht_hi + (size_t)b*65536;
  const ushort* hlb = ht_lo + (size_t)b*65536;

  const uint4 Z16 = make_uint4(0,0,0,0);
  for (int idx = tid; idx < 1728; idx += 512){
    int slot = idx >> 5, c = idx & 31;
    int rr = slot / 18, xi = slot - rr*18;
    int gy = ytile - 1 + rr, gx = x0 - 1 + xi;
    bool valid = (gy >= 0) & (gy < 32) & (gx >= 0) & (gx < 32);
    int px = gy*32 + gx;
    uint4 v = Z16;
    if (valid){
      if (c < 8)       v = *reinterpret_cast<const uint4*>(xb  + (size_t)px*64 + c*8);
      else if (c < 16) v = *reinterpret_cast<const uint4*>(hb  + (size_t)px*64 + (c-8)*8);
      else if (c < 24) v = *reinterpret_cast<const uint4*>(hlb + (size_t)px*64 + (c-16)*8);
      else if (flag)   v = *reinterpret_cast<const uint4*>(xlb + (size_t)px*64 + (c-24)*8);
    }
    *reinterpret_cast<uint4*>(&bsm[slot*264 + c*8]) = v;
  }
  __syncthreads();

  int w = tid >> 6, lane = tid & 63, lr = lane & 15, lk = lane >> 4;
  int m0 = w * 32;
  int px = nt*16 + lr;

  float4v acc[2];
  acc[0] = (float4v){0.f,0.f,0.f,0.f};
  acc[1] = (float4v){0.f,0.f,0.f,0.f};

  // wave-invariant part of the A row address
  const size_t abase = (size_t)(m0 + lr)*128 + lk*8;

  if (!flag){
    // -------- bf16 path: branch-free, double-buffered A prefetch --------
    short8v Aa[2][4], Ab[2][4];
    {
      #pragma unroll
      for (int mf = 0; mf < 2; ++mf){
        const ushort* ar = wa_hi + (size_t)(0*256 + mf*16)*128 + abase;
        Aa[mf][0]=ldfrag(ar); Aa[mf][1]=ldfrag(ar+32);
        Aa[mf][2]=ldfrag(ar+64); Aa[mf][3]=ldfrag(ar+96);
      }
    }
    #pragma unroll
    for (int p = 0; p < 9; ++p){
      // prefetch next p into the alternate buffer
      if (p < 8){
        #pragma unroll
        for (int mf = 0; mf < 2; ++mf){
          const ushort* ar = wa_hi + (size_t)((p+1)*256 + mf*16)*128 + abase;
          if (p & 1){
            Aa[mf][0]=ldfrag(ar); Aa[mf][1]=ldfrag(ar+32);
            Aa[mf][2]=ldfrag(ar+64); Aa[mf][3]=ldfrag(ar+96);
          } else {
            Ab[mf][0]=ldfrag(ar); Ab[mf][1]=ldfrag(ar+32);
            Ab[mf][2]=ldfrag(ar+64); Ab[mf][3]=ldfrag(ar+96);
          }
        }
      }
      int pinl = (p/3)*18 + lr + (p%3);
      const ushort* bl = &bsm[pinl*264 + lk*8];
      short8v BX0 = ldfrag(bl),     BX1 = ldfrag(bl+32);
      short8v BH0 = ldfrag(bl+64),  BH1 = ldfrag(bl+96);
      short8v BL0 = ldfrag(bl+128), BL1 = ldfrag(bl+160);
      #pragma unroll
      for (int mf = 0; mf < 2; ++mf){
        short8v AX0 = (p & 1) ? Ab[mf][0] : Aa[mf][0];
        short8v AX1 = (p & 1) ? Ab[mf][1] : Aa[mf][1];
        short8v AH0 = (p & 1) ? Ab[mf][2] : Aa[mf][2];
        short8v AH1 = (p & 1) ? Ab[mf][3] : Aa[mf][3];
        acc[mf] = __builtin_amdgcn_mfma_f32_16x16x32_bf16(AX0, BX0, acc[mf], 0,0,0);
        acc[mf] = __builtin_amdgcn_mfma_f32_16x16x32_bf16(AX1, BX1, acc[mf], 0,0,0);
        acc[mf] = __builtin_amdgcn_mfma_f32_16x16x32_bf16(AH0, BH0, acc[mf], 0,0,0);
        acc[mf] = __builtin_amdgcn_mfma_f32_16x16x32_bf16(AH1, BH1, acc[mf], 0,0,0);
        acc[mf] = __builtin_amdgcn_mfma_f32_16x16x32_bf16(AH0, BL0, acc[mf], 0,0,0);
        acc[mf] = __builtin_amdgcn_mfma_f32_16x16x32_bf16(AH1, BL1, acc[mf], 0,0,0);
      }
    }
  } else {
    // -------- f32 path (cold; inputs were f32) --------
    #pragma unroll 1
    for (int p = 0; p < 9; ++p){
      int pinl = (p/3)*18 + lr + (p%3);
      const ushort* bl = &bsm[pinl*264 + lk*8];
      short8v BX0 = ldfrag(bl),      BX1 = ldfrag(bl+32);
      short8v BH0 = ldfrag(bl+64),   BH1 = ldfrag(bl+96);
      short8v BL0 = ldfrag(bl+128),  BL1 = ldfrag(bl+160);
      short8v BXl0 = ldfrag(bl+192), BXl1 = ldfrag(bl+224);
      #pragma unroll
      for (int mf = 0; mf < 2; ++mf){
        const ushort* ar  = wa_hi + (size_t)(p*256 + mf*16)*128 + abase;
        const ushort* arl = wa_lo + (size_t)(p*256 + mf*16)*128 + abase;
        short8v AX0 = ldfrag(ar),     AX1 = ldfrag(ar+32);
        short8v AH0 = ldfrag(ar+64),  AH1 = ldfrag(ar+96);
        short8v AXl0 = ldfrag(arl),   AXl1 = ldfrag(arl+32);
        short8v AHl0 = ldfrag(arl+64),AHl1 = ldfrag(arl+96);
        acc[mf] = __builtin_amdgcn_mfma_f32_16x16x32_bf16(AX0, BX0, acc[mf], 0,0,0);
        acc[mf] = __builtin_amdgcn_mfma_f32_16x16x32_bf16(AX1, BX1, acc[mf], 0,0,0);
        acc[mf] = __builtin_amdgcn_mfma_f32_16x16x32_bf16(AH0, BH0, acc[mf], 0,0,0);
        acc[mf] = __builtin_amdgcn_mfma_f32_16x16x32_bf16(AH1, BH1, acc[mf], 0,0,0);
        acc[mf] = __builtin_amdgcn_mfma_f32_16x16x32_bf16(AH0, BL0, acc[mf], 0,0,0);
        acc[mf] = __builtin_amdgcn_mfma_f32_16x16x32_bf16(AH1, BL1, acc[mf], 0,0,0);
        acc[mf] = __builtin_amdgcn_mfma_f32_16x16x32_bf16(AX0,  BXl0, acc[mf], 0,0,0);
        acc[mf] = __builtin_amdgcn_mfma_f32_16x16x32_bf16(AX1,  BXl1, acc[mf], 0,0,0);
        acc[mf] = __builtin_amdgcn_mfma_f32_16x16x32_bf16(AXl0, BX0,  acc[mf], 0,0,0);
        acc[mf] = __builtin_amdgcn_mfma_f32_16x16x32_bf16(AXl1, BX1,  acc[mf], 0,0,0);
        acc[mf] = __builtin_amdgcn_mfma_f32_16x16x32_bf16(AHl0, BH0,  acc[mf], 0,0,0);
        acc[mf] = __builtin_amdgcn_mfma_f32_16x16x32_bf16(AHl1, BH1,  acc[mf], 0,0,0);
      }
    }
  }

  #pragma unroll
  for (int mf=0; mf<2; ++mf){
    int cc = w*8 + mf*4 + lk;
    int wi = cc*1024 + px;
    size_t sidx = ((size_t)(b*64 + cc))*1024 + px;
    float cprev = cst[sidx];
    float ic = acc[mf][0] + smalls[O_CB + cc];
    float fc = acc[mf][1] + smalls[O_CB + 64 + cc];
    float gc = acc[mf][2] + smalls[O_CB + 128 + cc];
    float oc = acc[mf][3] + smalls[O_CB + 192 + cc];
    float ig = sigm(ic + smalls[O_WCI + wi]*cprev);
    float fg = sigm(fc + smalls[O_WCF + wi]*cprev);
    float cnew = fg*cprev + ig*tanhc(gc);
    float og = sigm(oc + smalls[O_WCO + wi]*cnew);
    cst[sidx]  = cnew;
    hnew[sidx] = og*tanhc(cnew);
  }
}

// ---------------------------------------------------------------------------
// 1x1 projections -> bf16 MFMA-ready buffers.
// grid (128 ntiles of 8, 4 b) = 512 blocks (2/CU), block 256
// ---------------------------------------------------------------------------
__global__ __launch_bounds__(256) void k_proj(
  const float* __restrict__ hnew, const float* __restrict__ mst,
  const float* __restrict__ smalls,
  ushort* __restrict__ qb16, ushort* __restrict__ khb16, ushort* __restrict__ kmb16,
  ushort* __restrict__ vth16, ushort* __restrict__ vtm16)
{
  __shared__ float hs[64*9];
  __shared__ float ms[64*9];
  int b = blockIdx.y, n0 = blockIdx.x*8;
  int tid = threadIdx.x, nl = tid&7, rg = tid>>3;
  for (int idx = tid; idx < 512; idx += 256){
    int nn = idx & 7, ch = idx >> 3;
    hs[ch*9+nn] = hnew[((size_t)b*64+ch)*1024 + n0 + nn];
    ms[ch*9+nn] = mst [((size_t)b*64+ch)*1024 + n0 + nn];
  }
  __syncthreads();
  int n = n0 + nl;
  for (int j = 0; j < 6; ++j){
    int r = rg + 32*j;
    if (r >= 176) break;
    const float* src; const float* wrow; float bias;
    int mode, rr;
    if (r < 16)      { mode=0; rr=r;     src = hs; wrow = smalls+O_QW  + rr*64; bias = smalls[O_QB+rr]; }
    else if (r < 32) { mode=1; rr=r-16;  src = hs; wrow = smalls+O_KW  + rr*64; bias = smalls[O_KB+rr]; }
    else if (r < 48) { mode=2; rr=r-32;  src = ms; wrow = smalls+O_K2W + rr*64; bias = smalls[O_K2B+rr]; }
    else if (r < 112){ mode=3; rr=r-48;  src = hs; wrow = smalls+O_VW  + rr*64; bias = smalls[O_VB+rr]; }
    else             { mode=4; rr=r-112; src = ms; wrow = smalls+O_V2W + rr*64; bias = smalls[O_V2B+rr]; }
    float acc = bias;
    #pragma unroll
    for (int c4 = 0; c4 < 16; ++c4){
      float4 w4 = *reinterpret_cast<const float4*>(wrow + c4*4);
      acc += w4.x*src[(c4*4+0)*9+nl] + w4.y*src[(c4*4+1)*9+nl]
           + w4.z*src[(c4*4+2)*9+nl] + w4.w*src[(c4*4+3)*9+nl];
    }
    ushort v = f2bu(acc);
    if (mode <= 2){
      ushort* base = (mode==0) ? qb16 : (mode==1) ? khb16 : kmb16;
      size_t o = ((size_t)b*1024 + n)*32;
      base[o + rr] = v;
      base[o + 16 + rr] = 0;
    } else {
      ushort* base = (mode==3) ? vth16 : vtm16;
      base[((size_t)b*64 + rr)*1024 + n] = v;
    }
  }
}

// ---------------------------------------------------------------------------
// MFMA flash attention. grid (64 ntiles of 16, 4 b, 2 br) = 512 blocks (2/CU),
// block 256 = 4 waves.
// ---------------------------------------------------------------------------
__global__ __launch_bounds__(256) void k_fatt(
  const ushort* __restrict__ qb16, const ushort* __restrict__ khb16,
  const ushort* __restrict__ kmb16, const ushort* __restrict__ vth16,
  const ushort* __restrict__ vtm16, float* __restrict__ zcat)
{
  __shared__ ushort es[16*272];
  __shared__ float rs_s[4][16];
  int n0 = blockIdx.x*16, b = blockIdx.y, br = blockIdx.z;
  const ushort* kb = (br ? kmb16 : khb16) + (size_t)b*32768;
  const ushort* vt = (br ? vtm16 : vth16) + (size_t)b*65536;
  const ushort* qp = qb16 + (size_t)b*32768;
  int tid = threadIdx.x;
  int w = tid >> 6, lane = tid & 63, lr = lane & 15, lk = lane >> 4;
  const float4v Z4 = {0.f,0.f,0.f,0.f};

  short8v qf = ldfrag(qp + (size_t)(n0 + lr)*32 + lk*8);

  float4v acc[2];
  acc[0]=Z4; acc[1]=Z4;
  float rsum = 0.f;

  #pragma unroll 1
  for (int mc = 0; mc < 4; ++mc){
    int mbase = mc*256 + w*64;
    #pragma unroll
    for (int tau = 0; tau < 4; ++tau){
      short8v af = ldfrag(kb + (size_t)(mbase + tau*16 + lr)*32 + lk*8);
      float4v d = __builtin_amdgcn_mfma_f32_16x16x32_bf16(af, qf, Z4, 0,0,0);
      ushort u0 = f2bu(__expf(fminf(d[0], 60.f)));
      ushort u1 = f2bu(__expf(fminf(d[1], 60.f)));
      ushort u2 = f2bu(__expf(fminf(d[2], 60.f)));
      ushort u3 = f2bu(__expf(fminf(d[3], 60.f)));
      rsum += (bu2f(u0) + bu2f(u1)) + (bu2f(u2) + bu2f(u3));
      unsigned lo = (unsigned)u0 | ((unsigned)u1 << 16);
      unsigned hi = (unsigned)u2 | ((unsigned)u3 << 16);
      *reinterpret_cast<uint2*>(&es[lr*272 + w*64 + tau*16 + lk*4]) = make_uint2(lo, hi);
    }
    __syncthreads();
    #pragma unroll
    for (int ks = 0; ks < 8; ++ks){
      short8v av = ldfrag(vt + (size_t)(w*16 + lr)*1024 + mc*256 + ks*32 + lk*8);
      short8v bv = ldfrag(&es[lr*272 + ks*32 + lk*8]);
      acc[ks & 1] = __builtin_amdgcn_mfma_f32_16x16x32_bf16(av, bv, acc[ks & 1], 0,0,0);
    }
    __syncthreads();
  }

  {
    float r = rsum;
    r += __shfl_xor(r, 16);
    r += __shfl_xor(r, 32);
    if (lane < 16) rs_s[w][lr] = r;
  }
  __syncthreads();
  {
    float rinv = 1.0f / (rs_s[0][lr] + rs_s[1][lr] + rs_s[2][lr] + rs_s[3][lr]);
    #pragma unroll
    for (int r = 0; r < 4; ++r){
      int c = w*16 + lk*4 + r;
      zcat[((size_t)(b*128 + br*64 + c))*1024 + n0 + lr] = (acc[0][r] + acc[1][r])*rinv;
    }
  }
}

// ---------------------------------------------------------------------------
// zcomb: zt = zwT^T@zcat+z_b; comb = mw4@[zt;hnew]+m_b; gate; h_out
// writes m state, hT_hi/lo bf16, and d_out
// ---------------------------------------------------------------------------
__global__ __launch_bounds__(256) void k_zcomb(
  const float* __restrict__ zcat, const float* __restrict__ hnew,
  const float* __restrict__ smalls, const float* __restrict__ zwT,
  const float* __restrict__ mw4, const int* __restrict__ flagp,
  float* __restrict__ mst, ushort* __restrict__ hth, ushort* __restrict__ htl,
  void* __restrict__ outraw, int t)
{
  __shared__ float zin[128*9];
  __shared__ float hl [64*9];
  __shared__ float ml [64*9];
  __shared__ float zt_s[8*132];
  __shared__ float ho_s[64*9];
  __shared__ float mn_s[64*9];
  int n0 = blockIdx.x*8, b = blockIdx.y;
  int tid = threadIdx.x;
  int px = tid >> 5, lr = tid & 31;
  int flag = *flagp;
  for (int idx = tid; idx < 1024; idx += 256){
    int ch = idx >> 3, pp = idx & 7;
    zin[ch*9+pp] = zcat[((size_t)b*128 + ch)*1024 + n0 + pp];
  }
  for (int idx = tid; idx < 512; idx += 256){
    int ch = idx >> 3, pp = idx & 7;
    hl[ch*9+pp] = hnew[((size_t)b*64 + ch)*1024 + n0 + pp];
    ml[ch*9+pp] = mst [((size_t)b*64 + ch)*1024 + n0 + pp];
  }
  __syncthreads();
  {
    float4 a4 = *reinterpret_cast<const float4*>(&smalls[O_ZB + lr*4]);
    float acc0=a4.x, acc1=a4.y, acc2=a4.z, acc3=a4.w;
    #pragma unroll 4
    for (int k = 0; k < 128; ++k){
      float zv = zin[k*9 + px];
      float4 w4 = *reinterpret_cast<const float4*>(&zwT[k*128 + lr*4]);
      acc0 += w4.x*zv; acc1 += w4.y*zv; acc2 += w4.z*zv; acc3 += w4.w*zv;
    }
    *reinterpret_cast<float4*>(&zt_s[px*132 + lr*4]) = make_float4(acc0,acc1,acc2,acc3);
  }
  __syncthreads();
  {
    float acc6[6];
    #pragma unroll
    for (int i=0;i<6;++i) acc6[i] = smalls[O_MB + lr + 32*i];
    #pragma unroll 2
    for (int k4 = 0; k4 < 32; ++k4){
      float4 xv = *reinterpret_cast<const float4*>(&zt_s[px*132 + k4*4]);
      const float* wb = mw4 + (size_t)(k4*192)*4;
      #pragma unroll
      for (int i=0;i<6;++i){
        float4 w = *reinterpret_cast<const float4*>(&wb[(lr + 32*i)*4]);
        acc6[i] += w.x*xv.x + w.y*xv.y + w.z*xv.z + w.w*xv.w;
      }
    }
    #pragma unroll 2
    for (int k4 = 32; k4 < 48; ++k4){
      int ch = (k4-32)*4;
      float4 xv = make_float4(hl[ch*9+px], hl[(ch+1)*9+px], hl[(ch+2)*9+px], hl[(ch+3)*9+px]);
      const float* wb = mw4 + (size_t)(k4*192)*4;
      #pragma unroll
      for (int i=0;i<6;++i){
        float4 w = *reinterpret_cast<const float4*>(&wb[(lr + 32*i)*4]);
        acc6[i] += w.x*xv.x + w.y*xv.y + w.z*xv.z + w.w*xv.w;
      }
    }
    #pragma unroll
    for (int j=0;j<2;++j){
      int ch = lr + 32*j;
      float mold = ml[ch*9 + px];
      float gi = sigm(acc6[4+j]);
      float mnew = (1.0f-gi)*mold + gi*tanhc(acc6[2+j]);
      float ho = sigm(acc6[j])*mnew;
      ho_s[ch*9+px] = ho;
      mn_s[ch*9+px] = mnew;
    }
  }
  __syncthreads();
  for (int idx = tid; idx < 512; idx += 256){
    int ch = idx >> 3, pp = idx & 7;
    int n = n0 + pp;
    size_t gidx = ((size_t)b*64 + ch)*1024 + n;
    mst[gidx] = mn_s[ch*9+pp];
    float ho = ho_s[ch*9+pp];
    size_t tix = ((size_t)b*1024 + n)*64 + ch;
    ushort hb_ = f2bu(ho);
    hth[tix] = hb_;
    htl[tix] = f2bu(ho - bu2f(hb_));
    size_t oidx = ((size_t)(b*64+ch)*8 + t)*1024 + n;
    if (flag) ((float*)outraw)[oidx] = ho;
    else      ((bf16*)outraw)[oidx] = __float2bfloat16(ho);
  }
}

extern "C" void kernel_launch(void* const* d_in, const int* in_sizes, int n_in,
                              void* d_out, int out_size, void* d_ws, size_t ws_size,
                              hipStream_t stream)
{
  float* ws = (float*)d_ws;
  int* flag = (int*)(ws + WS_FLAG);
  float* c    = ws + WS_C;
  float* m    = ws + WS_M;
  float* hnew = ws + WS_HNEW;
  float* zcat = ws + WS_ZCAT;
  float* zwT  = ws + WS_ZWT;
  float* mw4  = ws + WS_MW4;
  ushort* qb16  = (ushort*)(ws + WS_QB16);
  ushort* khb16 = (ushort*)(ws + WS_KHB16);
  ushort* kmb16 = (ushort*)(ws + WS_KMB16);
  ushort* vth16 = (ushort*)(ws + WS_VTH16);
  ushort* vtm16 = (ushort*)(ws + WS_VTM16);
  ushort* wa_hi = (ushort*)(ws + WS_WAHI);
  ushort* wa_lo = (ushort*)(ws + WS_WALO);
  ushort* xt_hi = (ushort*)(ws + WS_XTHI);
  ushort* xt_lo = (ushort*)(ws + WS_XTLO);
  ushort* ht_hi = (ushort*)(ws + WS_HTHI);
  ushort* ht_lo = (ushort*)(ws + WS_HTLO);

  k_probe<<<1, 256, 0, stream>>>((const unsigned int*)d_in[0], flag);
  P18 pk;
  for (int i = 0; i < 18; ++i) pk.p[i] = d_in[2 + i];
  k_wconv<<<dim3(64,18), 256, 0, stream>>>(pk, flag, ws);
  k_init<<<3072, 256, 0, stream>>>(d_in[1], flag, ws);
  k_xt<<<dim3(16,32), 256, 0, stream>>>(d_in[0], flag, ws);
  k_wtrans<<<144, 256, 0, stream>>>(ws);

  for (int t = 0; t < 8; ++t){
    k_conv_mfma<<<dim3(64,4), 512, 0, stream>>>(flag, wa_hi, wa_lo, xt_hi, xt_lo,
                                                ht_hi, ht_lo, ws, c, hnew, t);
    k_proj<<<dim3(128,4), 256, 0, stream>>>(hnew, m, ws, qb16, khb16, kmb16, vth16, vtm16);
    k_fatt<<<dim3(64,4,2), 256, 0, stream>>>(qb16, khb16, kmb16, vth16, vtm16, zcat);
    k_zcomb<<<dim3(128,4), 256, 0, stream>>>(zcat, hnew, ws, zwT, mw4, flag,
                                             m, ht_hi, ht_lo, d_out, t);
  }
  (void)in_sizes; (void)n_in; (void)out_size; (void)ws_size;
}